// Round 3
// baseline (805.161 us; speedup 1.0000x reference)
//
#include <hip/hip_runtime.h>
#include <stdint.h>

#define V_ELEMS (64*64*64)

typedef _Float16 f16x8 __attribute__((ext_vector_type(8)));
typedef _Float16 f16x4 __attribute__((ext_vector_type(4)));
typedef float f32x4 __attribute__((ext_vector_type(4)));

// LDS layout (bytes):
//   h  : [64][200] f16 @ 0      (25600)  token-major window input; per-wave oh scratch after hp loop
//   qk : [2][64][72] f16 @ 25600 (18432) q cols 0-31 (pre-scaled), k cols 32-63; aliased by P
//   vt : [64][72]  f16 @ 44032 (9216)   head-dim-major V (token cols)
// total 53248 -> 3 blocks/CU
#define SMEM_BYTES 53248
#define H_STRIDE 200
#define QKP_STRIDE 72
#define VT_STRIDE 72

__global__ void cvt_weights_kernel(const float* __restrict__ qkv_w,
                                   const float* __restrict__ proj_w,
                                   _Float16* __restrict__ w16) {
    int i = blockIdx.x * 256 + threadIdx.x;
    if (i < 110592)      w16[i] = (_Float16)qkv_w[i];
    else if (i < 147456) w16[i] = (_Float16)proj_w[i - 110592];
}

__global__ __launch_bounds__(256, 3)
void win_attn_kernel(const float* __restrict__ x,
                     const _Float16* __restrict__ w16,
                     const float* __restrict__ qkv_b,
                     const float* __restrict__ proj_b,
                     float* __restrict__ out)
{
    extern __shared__ char smem[];
    _Float16* h_s  = (_Float16*)smem;                    // [64][200]
    _Float16* qk_s = (_Float16*)(smem + 25600);          // [2][64][72]
    _Float16* P_s  = (_Float16*)(smem + 25600);          // alias qk
    _Float16* vt_s = (_Float16*)(smem + 44032);          // [64][72]

    const _Float16* qw16 = w16;            // [576][192]
    const _Float16* pw16 = w16 + 110592;   // [192][192]

    const int tid  = threadIdx.x;
    const int wave = tid >> 6;
    const int lane = tid & 63;
    const int l15  = lane & 15;
    const int quad = lane >> 4;

    // XCD-aware swizzle (kept from r2: net win on FETCH)
    const int bid = blockIdx.x;
    const int xcd = bid & 7;
    const int s_  = bid >> 3;
    const int wzl = s_ & 3;
    const int gi  = (s_ >> 2) * 8 + xcd;
    const int wx  = gi >> 6;
    const int wy  = (gi >> 2) & 15;
    const int wz  = ((gi & 3) << 2) | wzl;

    // ---- Phase 0: gather (with cyclic shift). lane = token, 8-ch f16x8 packs ----
    {
        const int tok = tid & 63;
        const int g   = tid >> 6;
        const int i = tok >> 4, j = (tok >> 2) & 3, tz = tok & 3;
        const int xg = (wx*4 + i + 2) & 63;
        const int yg = (wy*4 + j + 2) & 63;
        const int zg = (wz*4 + tz + 2) & 63;
        const size_t spat = ((size_t)xg*64 + (size_t)yg)*64 + (size_t)zg;
#pragma unroll
        for (int t = 0; t < 6; ++t) {
            const int c0 = (g + 4*t) * 8;
            const float* xp = x + (size_t)c0 * V_ELEMS + spat;
            f16x8 pk;
#pragma unroll
            for (int u = 0; u < 8; ++u) pk[u] = (_Float16)xp[(size_t)u * V_ELEMS];
            *(f16x8*)(h_s + tok*H_STRIDE + c0) = pk;
        }
    }

    const f32x4 fzero = {0.f, 0.f, 0.f, 0.f};
    f32x4 oacc[3][2][2];
#pragma unroll
    for (int a = 0; a < 3; ++a)
#pragma unroll
        for (int b = 0; b < 2; ++b)
#pragma unroll
            for (int c = 0; c < 2; ++c) oacc[a][b][c] = fzero;

    const float kl2e = 0.17677669529663687f * 1.4426950408889634f; // hd^-0.5 * log2(e)
    const f16x8 ones = {(_Float16)1.f,(_Float16)1.f,(_Float16)1.f,(_Float16)1.f,
                        (_Float16)1.f,(_Float16)1.f,(_Float16)1.f,(_Float16)1.f};

    __syncthreads();

#pragma unroll
    for (int hp = 0; hp < 3; ++hp) {
        // ---- Phase A: qkv GEMM for this head pair ----
#pragma unroll
        for (int tt = 0; tt < 3; ++tt) {
            const int t  = wave + 4*tt;
            const int wh = t >> 2;            // 0=q 1=k 2=v
            const int hh = (t >> 1) & 1;
            const int dh = t & 1;
            const int n  = wh*192 + (2*hp + hh)*32 + dh*16 + l15;
            f16x8 bfr[6];
#pragma unroll
            for (int ks = 0; ks < 6; ++ks)
                bfr[ks] = *(const f16x8*)(qw16 + (size_t)n*192 + ks*32 + quad*8);
            const float bias = qkv_b[n];
#pragma unroll
            for (int rt = 0; rt < 4; ++rt) {
                f32x4 acc = fzero;
#pragma unroll
                for (int ks = 0; ks < 6; ++ks) {
                    f16x8 af = *(const f16x8*)(h_s + (rt*16 + l15)*H_STRIDE + ks*32 + quad*8);
                    acc = __builtin_amdgcn_mfma_f32_16x16x32_f16(af, bfr[ks], acc, 0, 0, 0);
                }
                if (wh == 2) {
                    f16x4 pk;
#pragma unroll
                    for (int r2 = 0; r2 < 4; ++r2) pk[r2] = (_Float16)(acc[r2] + bias);
                    *(f16x4*)(vt_s + (hh*32 + dh*16 + l15)*VT_STRIDE + rt*16 + quad*4) = pk;
                } else {
                    _Float16* dst = qk_s + hh*64*QKP_STRIDE + (wh == 1 ? 32 : 0);
#pragma unroll
                    for (int r2 = 0; r2 < 4; ++r2) {
                        float v = acc[r2] + bias;
                        if (wh == 0) v *= kl2e;   // pre-scale q
                        dst[(rt*16 + quad*4 + r2)*QKP_STRIDE + dh*16 + l15] = (_Float16)v;
                    }
                }
            }
        }
        __syncthreads();   // q/k/vt ready

        // ---- Phase B: S = q k^T (own row-tile), exp (max-free), stage P~ ----
        f16x4 pf[2][4];
#pragma unroll
        for (int jj = 0; jj < 2; ++jj) {
            f16x8 aq = *(const f16x8*)(qk_s + (jj*64 + wave*16 + l15)*QKP_STRIDE + quad*8);
#pragma unroll
            for (int ct = 0; ct < 4; ++ct) {
                f16x8 bk = *(const f16x8*)(qk_s + (jj*64 + ct*16 + l15)*QKP_STRIDE + 32 + quad*8);
                f32x4 s = __builtin_amdgcn_mfma_f32_16x16x32_f16(aq, bk, fzero, 0, 0, 0);
#pragma unroll
                for (int r = 0; r < 4; ++r) pf[jj][ct][r] = (_Float16)exp2f(s[r]);
            }
        }
        __syncthreads();   // all waves done reading q/k -> P may overwrite
#pragma unroll
        for (int jj = 0; jj < 2; ++jj)
#pragma unroll
            for (int ct = 0; ct < 4; ++ct)
#pragma unroll
                for (int r = 0; r < 4; ++r)
                    P_s[(jj*64 + wave*16 + quad*4 + r)*QKP_STRIDE + ct*16 + l15] = pf[jj][ct][r];

        // ---- Phase C: O~ = P~ V + MFMA row-sums; normalize after (own rows only) ----
        f32x4 racc[2] = {fzero, fzero};
#pragma unroll
        for (int jj = 0; jj < 2; ++jj)
#pragma unroll
            for (int ks = 0; ks < 2; ++ks) {
                f16x8 ap = *(const f16x8*)(P_s + (jj*64 + wave*16 + l15)*QKP_STRIDE + ks*32 + quad*8);
                racc[jj] = __builtin_amdgcn_mfma_f32_16x16x32_f16(ap, ones, racc[jj], 0, 0, 0);
#pragma unroll
                for (int ct = 0; ct < 2; ++ct) {
                    f16x8 bv = *(const f16x8*)(vt_s + (jj*32 + ct*16 + l15)*VT_STRIDE + ks*32 + quad*8);
                    oacc[hp][jj][ct] =
                        __builtin_amdgcn_mfma_f32_16x16x32_f16(ap, bv, oacc[hp][jj][ct], 0, 0, 0);
                }
            }
#pragma unroll
        for (int jj = 0; jj < 2; ++jj)
#pragma unroll
            for (int r = 0; r < 4; ++r) {
                const float inv = __builtin_amdgcn_rcpf(racc[jj][r]);
                oacc[hp][jj][0][r] *= inv;
                oacc[hp][jj][1][r] *= inv;
            }
        if (hp < 2) __syncthreads();   // next A overwrites qk(P) and vt
    }

    // ---- Proj: per-wave private oh round-trip into (dead) h region, no barriers ----
    {
        _Float16* ohp = h_s + wave*16*H_STRIDE;   // [16][200], ch in cols 0..191
#pragma unroll
        for (int hp = 0; hp < 3; ++hp)
#pragma unroll
            for (int jj = 0; jj < 2; ++jj)
#pragma unroll
                for (int ct = 0; ct < 2; ++ct)
#pragma unroll
                    for (int r = 0; r < 4; ++r)
                        ohp[(quad*4 + r)*H_STRIDE + hp*64 + jj*32 + ct*16 + l15] =
                            (_Float16)oacc[hp][jj][ct][r];
        f16x8 afr[6];
#pragma unroll
        for (int ks = 0; ks < 6; ++ks)
            afr[ks] = *(const f16x8*)(ohp + l15*H_STRIDE + ks*32 + quad*8);

        const int xg = (wx*4 + wave + 2) & 63;
        const int yg = (wy*4 + quad + 2) & 63;
        const int zA = wz*4 + 2;
        const int zB = (wz*4 + 4) & 63;
#pragma unroll
        for (int nt = 0; nt < 12; ++nt) {
            const int n = nt*16 + l15;
            f32x4 pacc = fzero;
#pragma unroll
            for (int ks = 0; ks < 6; ++ks) {
                f16x8 bw = *(const f16x8*)(pw16 + (size_t)n*192 + ks*32 + quad*8);
                pacc = __builtin_amdgcn_mfma_f32_16x16x32_f16(afr[ks], bw, pacc, 0, 0, 0);
            }
            const float bias = proj_b[n];
            const size_t base = (((size_t)n*64 + (size_t)xg)*64 + (size_t)yg)*64;
            float2 v01 = { pacc[0] + bias, pacc[1] + bias };
            float2 v23 = { pacc[2] + bias, pacc[3] + bias };
            *(float2*)(out + base + zA) = v01;
            *(float2*)(out + base + zB) = v23;
        }
    }
}

extern "C" void kernel_launch(void* const* d_in, const int* in_sizes, int n_in,
                              void* d_out, int out_size, void* d_ws, size_t ws_size,
                              hipStream_t stream) {
    const float* x      = (const float*)d_in[0];
    const float* qkv_w  = (const float*)d_in[1];
    const float* qkv_b  = (const float*)d_in[2];
    const float* proj_w = (const float*)d_in[3];
    const float* proj_b = (const float*)d_in[4];
    float* out = (float*)d_out;
    _Float16* w16 = (_Float16*)d_ws;   // 147456 f16 = 294912 B

    cvt_weights_kernel<<<dim3(576), dim3(256), 0, stream>>>(qkv_w, proj_w, w16);
    win_attn_kernel<<<dim3(4096), dim3(256), SMEM_BYTES, stream>>>(
        x, w16, qkv_b, proj_b, out);
}